// Round 1
// baseline (1144.832 us; speedup 1.0000x reference)
//
#include <hip/hip_runtime.h>
#include <hip/hip_bf16.h>

// Problem: N=100000 nodes (D=128), E=1600000 edges, C=2.
// reference: src_hid = x[src]@W_src^T+b_src ; dst_hid = x[dst]@W_dst^T+b_dst
//            edge_embs = relu(src_hid + dst_hid)          [E,128]
//            score     = edge_embs@W_out^T + b_out        [E,2]
// outputs concatenated: d_out = [score (E*2) | edge_embs (E*128)], fp32.
//
// Strategy: per-NODE precompute H[n][0:128] = x[n]@W_src^T+b_src,
//                               H[n][128:256]= x[n]@W_dst^T+b_dst   (in d_ws)
// (16.4x FLOP reduction vs per-edge GEMM), then a memory-bound per-edge
// gather+add+relu+tiny-dot kernel.

// ---------------------------------------------------------------------------
// Kernel 1: H = [x@Wsrc^T+bsrc | x@Wdst^T+bdst]   (fp32 tiled GEMM)
// grid = (ceil(N/128), 2)  blockIdx.y==0 -> src half, ==1 -> dst half
// block = 256 threads, 8x8 per-thread micro-tile, BK=32, LDS-staged transposed.
// ---------------------------------------------------------------------------
__global__ __launch_bounds__(256) void hid_gemm(
    const float* __restrict__ x,
    const float* __restrict__ Wsrc, const float* __restrict__ bsrc,
    const float* __restrict__ Wdst, const float* __restrict__ bdst,
    float* __restrict__ H, int N)
{
    constexpr int BM = 128, BK = 32, LDA = BM + 4;  // LDA*4B = 528 = 33*16 (keeps float4 alignment)
    __shared__ float As[BK][LDA];   // As[k][m] = x[m0+m][k0+k]
    __shared__ float Bs[BK][LDA];   // Bs[k][h] = W[h][k0+k]

    const int mb = blockIdx.x;
    const int nb = blockIdx.y;
    const float* __restrict__ W    = nb ? Wdst : Wsrc;
    const float* __restrict__ bias = nb ? bdst : bsrc;
    const int m0  = mb * BM;
    const int tid = threadIdx.x;
    const int tm  = tid >> 4;   // 0..15 (row group)
    const int tn  = tid & 15;   // 0..15 (col group)

    float acc[8][8];
#pragma unroll
    for (int i = 0; i < 8; ++i)
#pragma unroll
        for (int j = 0; j < 8; ++j) acc[i][j] = 0.0f;

    for (int k0 = 0; k0 < 128; k0 += BK) {
        // Stage x tile and W tile, transposed into LDS.
        // 128 rows x 32 cols = 1024 float4 per tile; 4 float4 per thread per tile.
#pragma unroll
        for (int i = 0; i < 4; ++i) {
            const int f4 = tid + i * 256;      // 0..1023
            const int m  = f4 >> 3;            // row within tile (also = h for W)
            const int kk = (f4 & 7) << 2;      // k within tile (float4 granule)
            const int gm = m0 + m;
            float4 v = make_float4(0.f, 0.f, 0.f, 0.f);
            if (gm < N) v = *(const float4*)&x[(size_t)gm * 128 + k0 + kk];
            As[kk + 0][m] = v.x; As[kk + 1][m] = v.y;
            As[kk + 2][m] = v.z; As[kk + 3][m] = v.w;
            const float4 w = *(const float4*)&W[(size_t)m * 128 + k0 + kk];
            Bs[kk + 0][m] = w.x; Bs[kk + 1][m] = w.y;
            Bs[kk + 2][m] = w.z; Bs[kk + 3][m] = w.w;
        }
        __syncthreads();

#pragma unroll
        for (int k = 0; k < BK; ++k) {
            float a[8], b[8];
            *(float4*)&a[0] = *(const float4*)&As[k][tm * 8];
            *(float4*)&a[4] = *(const float4*)&As[k][tm * 8 + 4];
            *(float4*)&b[0] = *(const float4*)&Bs[k][tn * 8];
            *(float4*)&b[4] = *(const float4*)&Bs[k][tn * 8 + 4];
#pragma unroll
            for (int i = 0; i < 8; ++i)
#pragma unroll
                for (int j = 0; j < 8; ++j)
                    acc[i][j] = fmaf(a[i], b[j], acc[i][j]);
        }
        __syncthreads();
    }

    // Epilogue: H[gm][nb*128 + h] = acc + bias
#pragma unroll
    for (int i = 0; i < 8; ++i) {
        const int gm = m0 + tm * 8 + i;
        if (gm < N) {
#pragma unroll
            for (int j = 0; j < 8; j += 4) {
                const int h = tn * 8 + j;
                float4 o;
                o.x = acc[i][j + 0] + bias[h + 0];
                o.y = acc[i][j + 1] + bias[h + 1];
                o.z = acc[i][j + 2] + bias[h + 2];
                o.w = acc[i][j + 3] + bias[h + 3];
                *(float4*)&H[(size_t)gm * 256 + nb * 128 + h] = o;
            }
        }
    }
}

// ---------------------------------------------------------------------------
// Kernel 2: per-edge gather + add + relu + C=2 score.
// 32 lanes per edge (each lane owns a float4 of the 128-dim row);
// 8 edges per 256-thread block per iteration; grid-stride.
// ---------------------------------------------------------------------------
__global__ __launch_bounds__(256) void edge_score(
    const float* __restrict__ H,
    const int* __restrict__ src, const int* __restrict__ dst,
    const float* __restrict__ Wout, const float* __restrict__ bout,
    float* __restrict__ score, float* __restrict__ emb, long long E)
{
    const int lane = threadIdx.x & 31;
    const int grp  = threadIdx.x >> 5;
    long long g = (long long)blockIdx.x * 8 + grp;
    const long long stride = (long long)gridDim.x * 8;

    const float4 w0 = *(const float4*)&Wout[lane * 4];
    const float4 w1 = *(const float4*)&Wout[128 + lane * 4];
    const float  b0 = bout[0], b1 = bout[1];

    for (long long e = g; e < E; e += stride) {
        const int si = src[e];
        const int di = dst[e];
        const float4 s = *(const float4*)&H[(size_t)si * 256 + lane * 4];
        const float4 d = *(const float4*)&H[(size_t)di * 256 + 128 + lane * 4];
        float4 v;
        v.x = fmaxf(s.x + d.x, 0.0f);
        v.y = fmaxf(s.y + d.y, 0.0f);
        v.z = fmaxf(s.z + d.z, 0.0f);
        v.w = fmaxf(s.w + d.w, 0.0f);
        *(float4*)&emb[(size_t)e * 128 + lane * 4] = v;

        float c0 = v.x * w0.x + v.y * w0.y + v.z * w0.z + v.w * w0.w;
        float c1 = v.x * w1.x + v.y * w1.y + v.z * w1.z + v.w * w1.w;
#pragma unroll
        for (int off = 16; off; off >>= 1) {
            c0 += __shfl_xor(c0, off, 32);
            c1 += __shfl_xor(c1, off, 32);
        }
        if (lane == 0) {
            *(float2*)&score[e * 2] = make_float2(c0 + b0, c1 + b1);
        }
    }
}

// ---------------------------------------------------------------------------
// Fallback (only if ws_size < N*256*4): fused per-edge compute, no workspace.
// Correct but ~16x more FLOPs. 32 lanes per edge; x rows staged in LDS.
// ---------------------------------------------------------------------------
__global__ __launch_bounds__(256) void edge_direct(
    const float* __restrict__ x,
    const int* __restrict__ src, const int* __restrict__ dst,
    const float* __restrict__ Wsrc, const float* __restrict__ bsrc,
    const float* __restrict__ Wdst, const float* __restrict__ bdst,
    const float* __restrict__ Wout, const float* __restrict__ bout,
    float* __restrict__ score, float* __restrict__ emb, long long E)
{
    __shared__ float xs[8][2][128];
    const int lane = threadIdx.x & 31;
    const int grp  = threadIdx.x >> 5;
    const long long g = (long long)blockIdx.x * 8 + grp;
    const long long stride = (long long)gridDim.x * 8;

    const float4 w0 = *(const float4*)&Wout[lane * 4];
    const float4 w1 = *(const float4*)&Wout[128 + lane * 4];
    const float  b0 = bout[0], b1 = bout[1];
    float bias[4];
#pragma unroll
    for (int j = 0; j < 4; ++j) bias[j] = bsrc[lane * 4 + j] + bdst[lane * 4 + j];

    const long long iters = (E + stride - 1) / stride;
    for (long long it = 0; it < iters; ++it) {
        const long long e = g + it * stride;
        const bool act = (e < E);
        if (act) {
            const int si = src[e];
            const int di = dst[e];
            *(float4*)&xs[grp][0][lane * 4] = *(const float4*)&x[(size_t)si * 128 + lane * 4];
            *(float4*)&xs[grp][1][lane * 4] = *(const float4*)&x[(size_t)di * 128 + lane * 4];
        }
        __syncthreads();
        if (act) {
            float acc[4] = {bias[0], bias[1], bias[2], bias[3]};
            for (int k = 0; k < 128; k += 4) {
                const float4 a4 = *(const float4*)&xs[grp][0][k];
                const float4 c4 = *(const float4*)&xs[grp][1][k];
#pragma unroll
                for (int j = 0; j < 4; ++j) {
                    const float4 ws = *(const float4*)&Wsrc[(size_t)(lane * 4 + j) * 128 + k];
                    const float4 wd = *(const float4*)&Wdst[(size_t)(lane * 4 + j) * 128 + k];
                    acc[j] += a4.x * ws.x + a4.y * ws.y + a4.z * ws.z + a4.w * ws.w
                            + c4.x * wd.x + c4.y * wd.y + c4.z * wd.z + c4.w * wd.w;
                }
            }
            float4 v = make_float4(fmaxf(acc[0], 0.f), fmaxf(acc[1], 0.f),
                                   fmaxf(acc[2], 0.f), fmaxf(acc[3], 0.f));
            *(float4*)&emb[(size_t)e * 128 + lane * 4] = v;
            float c0 = v.x * w0.x + v.y * w0.y + v.z * w0.z + v.w * w0.w;
            float c1 = v.x * w1.x + v.y * w1.y + v.z * w1.z + v.w * w1.w;
#pragma unroll
            for (int off = 16; off; off >>= 1) {
                c0 += __shfl_xor(c0, off, 32);
                c1 += __shfl_xor(c1, off, 32);
            }
            if (lane == 0) *(float2*)&score[e * 2] = make_float2(c0 + b0, c1 + b1);
        }
        __syncthreads();
    }
}

// ---------------------------------------------------------------------------
extern "C" void kernel_launch(void* const* d_in, const int* in_sizes, int n_in,
                              void* d_out, int out_size, void* d_ws, size_t ws_size,
                              hipStream_t stream) {
    const float* x    = (const float*)d_in[0];
    const int*   src  = (const int*)d_in[1];
    const int*   dst  = (const int*)d_in[2];
    const float* Wsrc = (const float*)d_in[3];
    const float* bsrc = (const float*)d_in[4];
    const float* Wdst = (const float*)d_in[5];
    const float* bdst = (const float*)d_in[6];
    const float* Wout = (const float*)d_in[7];
    const float* bout = (const float*)d_in[8];

    const int       N = in_sizes[0] / 128;
    const long long E = in_sizes[1];

    float* score = (float*)d_out;
    float* emb   = score + (size_t)E * 2;   // outputs concatenated: [score | edge_embs]

    const size_t need = (size_t)N * 256 * sizeof(float);
    if (ws_size >= need) {
        float* H = (float*)d_ws;
        dim3 g1((N + 127) / 128, 2);
        hid_gemm<<<g1, dim3(256), 0, stream>>>(x, Wsrc, bsrc, Wdst, bdst, H, N);
        edge_score<<<dim3(8192), dim3(256), 0, stream>>>(H, src, dst, Wout, bout,
                                                         score, emb, E);
    } else {
        edge_direct<<<dim3(8192), dim3(256), 0, stream>>>(x, src, dst, Wsrc, bsrc,
                                                          Wdst, bdst, Wout, bout,
                                                          score, emb, E);
    }
}

// Round 2
// 1128.307 us; speedup vs baseline: 1.0146x; 1.0146x over previous
//
#include <hip/hip_runtime.h>
#include <hip/hip_bf16.h>

// Problem: N=100000 nodes (D=128), E=1600000 edges, C=2.
// reference: src_hid = x[src]@W_src^T+b_src ; dst_hid = x[dst]@W_dst^T+b_dst
//            edge_embs = relu(src_hid + dst_hid)          [E,128]
//            score     = edge_embs@W_out^T + b_out        [E,2]
// outputs concatenated: d_out = [score (E*2) | edge_embs (E*128)], fp32.
//
// Strategy: per-NODE precompute H[n][0:128] = x[n]@W_src^T+b_src,
//                               H[n][128:256]= x[n]@W_dst^T+b_dst   (in d_ws)
// (16.4x FLOP reduction vs per-edge GEMM), then a memory-bound per-edge
// gather+add+relu+tiny-dot kernel.
//
// R1 change: edge_score's emb/score stores are NON-TEMPORAL (nt) so the
// 832 MB output stream does not evict H (102 MB) from L2/L3. H gathers
// should then hit Infinity Cache instead of HBM.

typedef float f32x4 __attribute__((ext_vector_type(4)));
typedef float f32x2 __attribute__((ext_vector_type(2)));

// ---------------------------------------------------------------------------
// Kernel 1: H = [x@Wsrc^T+bsrc | x@Wdst^T+bdst]   (fp32 tiled GEMM)
// grid = (ceil(N/128), 2)  blockIdx.y==0 -> src half, ==1 -> dst half
// block = 256 threads, 8x8 per-thread micro-tile, BK=32, LDS-staged transposed.
// ---------------------------------------------------------------------------
__global__ __launch_bounds__(256) void hid_gemm(
    const float* __restrict__ x,
    const float* __restrict__ Wsrc, const float* __restrict__ bsrc,
    const float* __restrict__ Wdst, const float* __restrict__ bdst,
    float* __restrict__ H, int N)
{
    constexpr int BM = 128, BK = 32, LDA = BM + 4;  // LDA*4B = 528 (33*16: float4-aligned rows)
    __shared__ float As[BK][LDA];   // As[k][m] = x[m0+m][k0+k]
    __shared__ float Bs[BK][LDA];   // Bs[k][h] = W[h][k0+k]

    const int mb = blockIdx.x;
    const int nb = blockIdx.y;
    const float* __restrict__ W    = nb ? Wdst : Wsrc;
    const float* __restrict__ bias = nb ? bdst : bsrc;
    const int m0  = mb * BM;
    const int tid = threadIdx.x;
    const int tm  = tid >> 4;   // 0..15 (row group)
    const int tn  = tid & 15;   // 0..15 (col group)

    float acc[8][8];
#pragma unroll
    for (int i = 0; i < 8; ++i)
#pragma unroll
        for (int j = 0; j < 8; ++j) acc[i][j] = 0.0f;

    for (int k0 = 0; k0 < 128; k0 += BK) {
        // Stage x tile and W tile, transposed into LDS.
        // 128 rows x 32 cols = 1024 float4 per tile; 4 float4 per thread per tile.
#pragma unroll
        for (int i = 0; i < 4; ++i) {
            const int f4 = tid + i * 256;      // 0..1023
            const int m  = f4 >> 3;            // row within tile (also = h for W)
            const int kk = (f4 & 7) << 2;      // k within tile (float4 granule)
            const int gm = m0 + m;
            float4 v = make_float4(0.f, 0.f, 0.f, 0.f);
            if (gm < N) v = *(const float4*)&x[(size_t)gm * 128 + k0 + kk];
            As[kk + 0][m] = v.x; As[kk + 1][m] = v.y;
            As[kk + 2][m] = v.z; As[kk + 3][m] = v.w;
            const float4 w = *(const float4*)&W[(size_t)m * 128 + k0 + kk];
            Bs[kk + 0][m] = w.x; Bs[kk + 1][m] = w.y;
            Bs[kk + 2][m] = w.z; Bs[kk + 3][m] = w.w;
        }
        __syncthreads();

#pragma unroll
        for (int k = 0; k < BK; ++k) {
            float a[8], b[8];
            *(float4*)&a[0] = *(const float4*)&As[k][tm * 8];
            *(float4*)&a[4] = *(const float4*)&As[k][tm * 8 + 4];
            *(float4*)&b[0] = *(const float4*)&Bs[k][tn * 8];
            *(float4*)&b[4] = *(const float4*)&Bs[k][tn * 8 + 4];
#pragma unroll
            for (int i = 0; i < 8; ++i)
#pragma unroll
                for (int j = 0; j < 8; ++j)
                    acc[i][j] = fmaf(a[i], b[j], acc[i][j]);
        }
        __syncthreads();
    }

    // Epilogue: H[gm][nb*128 + h] = acc + bias   (regular stores: we WANT H cached)
#pragma unroll
    for (int i = 0; i < 8; ++i) {
        const int gm = m0 + tm * 8 + i;
        if (gm < N) {
#pragma unroll
            for (int j = 0; j < 8; j += 4) {
                const int h = tn * 8 + j;
                float4 o;
                o.x = acc[i][j + 0] + bias[h + 0];
                o.y = acc[i][j + 1] + bias[h + 1];
                o.z = acc[i][j + 2] + bias[h + 2];
                o.w = acc[i][j + 3] + bias[h + 3];
                *(float4*)&H[(size_t)gm * 256 + nb * 128 + h] = o;
            }
        }
    }
}

// ---------------------------------------------------------------------------
// Kernel 2: per-edge gather + add + relu + C=2 score.
// 32 lanes per edge (each lane owns a float4 of the 128-dim row);
// 8 edges per 256-thread block per iteration; grid-stride.
// emb/score stores are non-temporal to preserve H's L3 residency.
// ---------------------------------------------------------------------------
__global__ __launch_bounds__(256) void edge_score(
    const float* __restrict__ H,
    const int* __restrict__ src, const int* __restrict__ dst,
    const float* __restrict__ Wout, const float* __restrict__ bout,
    float* __restrict__ score, float* __restrict__ emb, long long E)
{
    const int lane = threadIdx.x & 31;
    const int grp  = threadIdx.x >> 5;
    long long g = (long long)blockIdx.x * 8 + grp;
    const long long stride = (long long)gridDim.x * 8;

    const float4 w0 = *(const float4*)&Wout[lane * 4];
    const float4 w1 = *(const float4*)&Wout[128 + lane * 4];
    const float  b0 = bout[0], b1 = bout[1];

    for (long long e = g; e < E; e += stride) {
        const int si = src[e];
        const int di = dst[e];
        const float4 s = *(const float4*)&H[(size_t)si * 256 + lane * 4];
        const float4 d = *(const float4*)&H[(size_t)di * 256 + 128 + lane * 4];
        float4 v;
        v.x = fmaxf(s.x + d.x, 0.0f);
        v.y = fmaxf(s.y + d.y, 0.0f);
        v.z = fmaxf(s.z + d.z, 0.0f);
        v.w = fmaxf(s.w + d.w, 0.0f);
        f32x4 vv = { v.x, v.y, v.z, v.w };
        __builtin_nontemporal_store(vv, (f32x4*)&emb[(size_t)e * 128 + lane * 4]);

        float c0 = v.x * w0.x + v.y * w0.y + v.z * w0.z + v.w * w0.w;
        float c1 = v.x * w1.x + v.y * w1.y + v.z * w1.z + v.w * w1.w;
#pragma unroll
        for (int off = 16; off; off >>= 1) {
            c0 += __shfl_xor(c0, off, 32);
            c1 += __shfl_xor(c1, off, 32);
        }
        if (lane == 0) {
            f32x2 sc = { c0 + b0, c1 + b1 };
            __builtin_nontemporal_store(sc, (f32x2*)&score[e * 2]);
        }
    }
}

// ---------------------------------------------------------------------------
// Fallback (only if ws_size < N*256*4): fused per-edge compute, no workspace.
// Correct but ~16x more FLOPs. 32 lanes per edge; x rows staged in LDS.
// ---------------------------------------------------------------------------
__global__ __launch_bounds__(256) void edge_direct(
    const float* __restrict__ x,
    const int* __restrict__ src, const int* __restrict__ dst,
    const float* __restrict__ Wsrc, const float* __restrict__ bsrc,
    const float* __restrict__ Wdst, const float* __restrict__ bdst,
    const float* __restrict__ Wout, const float* __restrict__ bout,
    float* __restrict__ score, float* __restrict__ emb, long long E)
{
    __shared__ float xs[8][2][128];
    const int lane = threadIdx.x & 31;
    const int grp  = threadIdx.x >> 5;
    const long long g = (long long)blockIdx.x * 8 + grp;
    const long long stride = (long long)gridDim.x * 8;

    const float4 w0 = *(const float4*)&Wout[lane * 4];
    const float4 w1 = *(const float4*)&Wout[128 + lane * 4];
    const float  b0 = bout[0], b1 = bout[1];
    float bias[4];
#pragma unroll
    for (int j = 0; j < 4; ++j) bias[j] = bsrc[lane * 4 + j] + bdst[lane * 4 + j];

    const long long iters = (E + stride - 1) / stride;
    for (long long it = 0; it < iters; ++it) {
        const long long e = g + it * stride;
        const bool act = (e < E);
        if (act) {
            const int si = src[e];
            const int di = dst[e];
            *(float4*)&xs[grp][0][lane * 4] = *(const float4*)&x[(size_t)si * 128 + lane * 4];
            *(float4*)&xs[grp][1][lane * 4] = *(const float4*)&x[(size_t)di * 128 + lane * 4];
        }
        __syncthreads();
        if (act) {
            float acc[4] = {bias[0], bias[1], bias[2], bias[3]};
            for (int k = 0; k < 128; k += 4) {
                const float4 a4 = *(const float4*)&xs[grp][0][k];
                const float4 c4 = *(const float4*)&xs[grp][1][k];
#pragma unroll
                for (int j = 0; j < 4; ++j) {
                    const float4 ws = *(const float4*)&Wsrc[(size_t)(lane * 4 + j) * 128 + k];
                    const float4 wd = *(const float4*)&Wdst[(size_t)(lane * 4 + j) * 128 + k];
                    acc[j] += a4.x * ws.x + a4.y * ws.y + a4.z * ws.z + a4.w * ws.w
                            + c4.x * wd.x + c4.y * wd.y + c4.z * wd.z + c4.w * wd.w;
                }
            }
            float4 v = make_float4(fmaxf(acc[0], 0.f), fmaxf(acc[1], 0.f),
                                   fmaxf(acc[2], 0.f), fmaxf(acc[3], 0.f));
            *(float4*)&emb[(size_t)e * 128 + lane * 4] = v;
            float c0 = v.x * w0.x + v.y * w0.y + v.z * w0.z + v.w * w0.w;
            float c1 = v.x * w1.x + v.y * w1.y + v.z * w1.z + v.w * w1.w;
#pragma unroll
            for (int off = 16; off; off >>= 1) {
                c0 += __shfl_xor(c0, off, 32);
                c1 += __shfl_xor(c1, off, 32);
            }
            if (lane == 0) *(float2*)&score[e * 2] = make_float2(c0 + b0, c1 + b1);
        }
        __syncthreads();
    }
}

// ---------------------------------------------------------------------------
extern "C" void kernel_launch(void* const* d_in, const int* in_sizes, int n_in,
                              void* d_out, int out_size, void* d_ws, size_t ws_size,
                              hipStream_t stream) {
    const float* x    = (const float*)d_in[0];
    const int*   src  = (const int*)d_in[1];
    const int*   dst  = (const int*)d_in[2];
    const float* Wsrc = (const float*)d_in[3];
    const float* bsrc = (const float*)d_in[4];
    const float* Wdst = (const float*)d_in[5];
    const float* bdst = (const float*)d_in[6];
    const float* Wout = (const float*)d_in[7];
    const float* bout = (const float*)d_in[8];

    const int       N = in_sizes[0] / 128;
    const long long E = in_sizes[1];

    float* score = (float*)d_out;
    float* emb   = score + (size_t)E * 2;   // outputs concatenated: [score | edge_embs]

    const size_t need = (size_t)N * 256 * sizeof(float);
    if (ws_size >= need) {
        float* H = (float*)d_ws;
        dim3 g1((N + 127) / 128, 2);
        hid_gemm<<<g1, dim3(256), 0, stream>>>(x, Wsrc, bsrc, Wdst, bdst, H, N);
        edge_score<<<dim3(8192), dim3(256), 0, stream>>>(H, src, dst, Wout, bout,
                                                         score, emb, E);
    } else {
        edge_direct<<<dim3(8192), dim3(256), 0, stream>>>(x, src, dst, Wsrc, bsrc,
                                                          Wdst, bdst, Wout, bout,
                                                          score, emb, E);
    }
}